// Round 10
// baseline (84.612 us; speedup 1.0000x reference)
//
#include <hip/hip_runtime.h>

#define BB 262144
#define TT 20
#define HH 10

static constexpr float L2E = 1.44269504088896340736f;

typedef float    f4 __attribute__((ext_vector_type(4)));
typedef _Float16 h4 __attribute__((ext_vector_type(4)));

#define MFMA16(A, B, C) __builtin_amdgcn_mfma_f32_16x16x16f16((A), (B), (C), 0, 0, 0)

__device__ __forceinline__ float frcp(float x)  { return __builtin_amdgcn_rcpf(x); }
__device__ __forceinline__ float fexp2(float x) { return __builtin_amdgcn_exp2f(x); }

// Slot map per g-group (same as R9):
//   g0: u0,u1,u2 | g1: u4,u5,u6 | g2: u8,u9,u3 | g3: u7, headA(a0..3), headB(a4)
// A rows prescaled: i,f,o by -L2E; g by +2*L2E; head rows raw.
// B (k=4g+e, col=s): g0: h0..h3 | g1: h4..h7 | g2: h8,h9,1,x | g3: dc (A==0 there).
// h3 (g2.tau2) and h7 (g3.tau0) swap home via one shfl_xor(32).
// DUAL-STREAM: wave covers seqs gw*32+s (stream0) and gw*32+16+s (stream1);
// two full STEP bodies interleave in one block to fill trans-latency bubbles.

// activation: ACC = (-L2E*i, -L2E*f, 2L2E*g, -L2E*o)
#define ACT(ACC, CC, HN) { \
        const float ei  = fexp2(ACC[0]); \
        const float ef  = fexp2(ACC[1]); \
        const float eg2 = fexp2(ACC[2]); \
        const float eo  = fexp2(ACC[3]); \
        const float t1 = 1.0f + ef, t2 = 1.0f + ei; \
        const float t3 = eg2 + 1.0f, t4 = eg2 - 1.0f; \
        const float t5 = t2 * t3; \
        const float cn = fmaf((CC), t5, t4 * t1) * frcp(t1 * t5); \
        (CC) = cn; \
        const float ec = fexp2(cn * (2.0f * L2E)); \
        (HN) = (ec - 1.0f) * frcp((1.0f + eo) * (ec + 1.0f)); \
    }

// one LSTM step for one stream; hA,hB,hC,c0,c1,c2 are lvalue register names
#define STEP(XT, hA, hB, hC, c0, c1, c2, SREF) { \
        const float msg = gIs3 ? (hA) : (hC); \
        const float rsw = __shfl_xor(msg, 32, 64); \
        const float B2f = gIs2 ? 1.0f : (hC); \
        const float B3f = gIs2 ? (XT) : rsw; \
        h4 Bf; \
        Bf[0] = (_Float16)(hA); Bf[1] = (_Float16)(hB); \
        Bf[2] = (_Float16)B2f;  Bf[3] = (_Float16)B3f; \
        const f4 z4 = {0.f, 0.f, 0.f, 0.f}; \
        f4 a0 = MFMA16(Af0, Bf, z4); \
        f4 a1 = MFMA16(Af1, Bf, z4); \
        f4 a2 = MFMA16(Af2, Bf, z4); \
        { \
            float zz = b2p; \
            float q0 = a1[0]; q0 = fmaxf(q0, 0.2f * q0); zz = fmaf(q0, w2p0, zz); \
            float q1 = a1[1]; q1 = fmaxf(q1, 0.2f * q1); zz = fmaf(q1, w2p1, zz); \
            float q2 = a1[2]; q2 = fmaxf(q2, 0.2f * q2); zz = fmaf(q2, w2p2, zz); \
            float q3 = a1[3]; q3 = fmaxf(q3, 0.2f * q3); zz = fmaf(q3, w2p3, zz); \
            float q4 = a2[0]; q4 = fmaxf(q4, 0.2f * q4); zz = fmaf(q4, w2p4, zz); \
            (SREF) = frcp(1.0f + fexp2(zz)); \
        } \
        ACT(a0, c0, hA) \
        ACT(a1, c1, hB) \
        ACT(a2, c2, hC) \
    }

__global__ __launch_bounds__(256) void lstm_disc_mfma(
    const float* __restrict__ values, const float* __restrict__ masks,
    const float* __restrict__ W_ih, const float* __restrict__ W_hh,
    const float* __restrict__ b_ih, const float* __restrict__ b_hh,
    const float* __restrict__ W1, const float* __restrict__ b1,
    const float* __restrict__ W2, const float* __restrict__ b2,
    const int* __restrict__ directp,
    float* __restrict__ out)
{
    const int tid = threadIdx.x;
    const int l   = tid & 63;
    const int g   = l >> 4;
    const int s   = l & 15;
    const int gw  = blockIdx.x * 4 + (tid >> 6);
    const int seq0 = gw * 32 + s;
    const int seq1 = seq0 + 16;
    const int dir = *directp;
    const bool gIs2 = (g == 2);
    const bool gIs3 = (g == 3);

    // ---- build A fragments once (shared by both streams) ----
    h4 Af0, Af1, Af2;
    {
        const int r  = s;
        const int G  = r >> 2;
        const int e  = r & 3;
        const int kb = g * 4;
        h4* afp[3] = {&Af0, &Af1, &Af2};
        #pragma unroll
        for (int tau = 0; tau < 3; ++tau) {
            int u;
            if (tau == 0)      u = (G == 0) ? 0 : (G == 1) ? 4 : (G == 2) ? 8 : 7;
            else if (tau == 1) u = (G == 0) ? 1 : (G == 1) ? 5 : (G == 2) ? 9 : -1;
            else               u = (G == 0) ? 2 : (G == 1) ? 6 : (G == 2) ? 3 : -2;
            float av0 = 0.f, av1 = 0.f, av2 = 0.f, av3 = 0.f;
            float* avp[4] = {&av0, &av1, &av2, &av3};
            #pragma unroll
            for (int e4 = 0; e4 < 4; ++e4) {
                const int k = kb + e4;
                float v = 0.0f;
                if (u >= 0) {
                    const int orow = 10 * e + u;
                    if (k < 10)       v = W_hh[orow * 10 + k];
                    else if (k == 10) v = b_ih[orow] + b_hh[orow];
                    else if (k == 11) v = W_ih[orow];
                    v *= (e == 2) ? (2.0f * L2E) : (-L2E);
                } else if (u == -1) {
                    if (k < 10)       v = W1[e * 10 + k];
                    else if (k == 10) v = b1[e];
                } else {
                    if (e == 0) {
                        if (k < 10)       v = W1[40 + k];
                        else if (k == 10) v = b1[4];
                    }
                }
                *avp[e4] = v;
            }
            h4 a;
            a[0] = (_Float16)av0; a[1] = (_Float16)av1;
            a[2] = (_Float16)av2; a[3] = (_Float16)av3;
            *afp[tau] = a;
        }
    }

    // head scalars, prescaled (wave-uniform -> SGPR)
    const float w2p0 = -L2E * W2[0], w2p1 = -L2E * W2[1], w2p2 = -L2E * W2[2],
                w2p3 = -L2E * W2[3], w2p4 = -L2E * W2[4];
    const float b2p = -L2E * b2[0];

    // ---- per-stream state ----
    float h0A = 0.f, h0B = 0.f, h0C = 0.f, c00 = 0.f, c01 = 0.f, c02 = 0.f;
    float h1A = 0.f, h1B = 0.f, h1C = 0.f, c10 = 0.f, c11 = 0.f, c12 = 0.f;

    // values: only g2 lanes feed x into B -> only they load (exec-masked)
    const float4* vr0 = reinterpret_cast<const float4*>(values + (size_t)seq0 * TT);
    const float4* vr1 = reinterpret_cast<const float4*>(values + (size_t)seq1 * TT);
    float4 cur0 = {0.f,0.f,0.f,0.f}, cur1 = {0.f,0.f,0.f,0.f};
    float4 nxt0 = {0.f,0.f,0.f,0.f}, nxt1 = {0.f,0.f,0.f,0.f};
    if (gIs2) { cur0 = vr0[dir ? 4 : 0]; cur1 = vr1[dir ? 4 : 0]; }

    // rotating score window (real on g3 lanes)
    float s00 = 0.f, s01 = 0.f, s02 = 0.f, s03 = 0.f;
    float s10 = 0.f, s11 = 0.f, s12 = 0.f, s13 = 0.f;
    float* orow0 = out + (size_t)seq0 * TT;
    float* orow1 = out + (size_t)seq1 * TT;

    #pragma unroll 1
    for (int q = 0; q < 5; ++q) {
        // prefetch next chunk (clamped; g2 lanes only)
        const int nq   = (q < 4) ? (q + 1) : 4;
        const int srcn = dir ? (4 - nq) : nq;
        if (gIs2) { nxt0 = vr0[srcn]; nxt1 = vr1[srcn]; }

        #pragma unroll
        for (int j = 0; j < 4; ++j) {
            const float e0f = (j == 0) ? cur0.x : (j == 1) ? cur0.y : (j == 2) ? cur0.z : cur0.w;
            const float e0r = (j == 0) ? cur0.w : (j == 1) ? cur0.z : (j == 2) ? cur0.y : cur0.x;
            const float e1f = (j == 0) ? cur1.x : (j == 1) ? cur1.y : (j == 2) ? cur1.z : cur1.w;
            const float e1r = (j == 0) ? cur1.w : (j == 1) ? cur1.z : (j == 2) ? cur1.y : cur1.x;
            const float xt0 = dir ? e0r : e0f;
            const float xt1 = dir ? e1r : e1f;

            float sv0, sv1;
            STEP(xt0, h0A, h0B, h0C, c00, c01, c02, sv0)
            STEP(xt1, h1A, h1B, h1C, c10, c11, c12, sv1)

            if (j == 0)      { s00 = sv0; s10 = sv1; }
            else if (j == 1) { s01 = sv0; s11 = sv1; }
            else if (j == 2) { s02 = sv0; s12 = sv1; }
            else             { s03 = sv0; s13 = sv1; }
        }

        if (gIs3) {
            float4 v0; v0.x = s00; v0.y = s01; v0.z = s02; v0.w = s03;
            float4 v1; v1.x = s10; v1.y = s11; v1.z = s12; v1.w = s13;
            *reinterpret_cast<float4*>(orow0 + q * 4) = v0;
            *reinterpret_cast<float4*>(orow1 + q * 4) = v1;
        }
        cur0 = nxt0; cur1 = nxt1;
    }

    // ---- masks pass-through: g0 -> stream0 row, g1 -> stream1 row ----
    if (g == 0) {
        const float* mrow = masks + (size_t)seq0 * TT;
        float* mout = out + (size_t)BB * TT + (size_t)seq0 * TT;
        if (dir == 0) {
            const float4* m4 = (const float4*)mrow;
            float4* o4 = (float4*)mout;
            #pragma unroll
            for (int i = 0; i < TT / 4; ++i) o4[i] = m4[i];
        } else {
            #pragma unroll
            for (int t = 0; t < TT; ++t) mout[t] = mrow[TT - 1 - t];
        }
    } else if (g == 1) {
        const float* mrow = masks + (size_t)seq1 * TT;
        float* mout = out + (size_t)BB * TT + (size_t)seq1 * TT;
        if (dir == 0) {
            const float4* m4 = (const float4*)mrow;
            float4* o4 = (float4*)mout;
            #pragma unroll
            for (int i = 0; i < TT / 4; ++i) o4[i] = m4[i];
        } else {
            #pragma unroll
            for (int t = 0; t < TT; ++t) mout[t] = mrow[TT - 1 - t];
        }
    }
}

extern "C" void kernel_launch(void* const* d_in, const int* in_sizes, int n_in,
                              void* d_out, int out_size, void* d_ws, size_t ws_size,
                              hipStream_t stream) {
    const float* values = (const float*)d_in[0];
    const float* masks  = (const float*)d_in[1];
    const float* W_ih   = (const float*)d_in[2];
    const float* W_hh   = (const float*)d_in[3];
    const float* b_ih   = (const float*)d_in[4];
    const float* b_hh   = (const float*)d_in[5];
    const float* W1     = (const float*)d_in[6];
    const float* b1     = (const float*)d_in[7];
    const float* W2     = (const float*)d_in[8];
    const float* b2     = (const float*)d_in[9];
    const int*   direct = (const int*)d_in[11];
    float* out = (float*)d_out;

    // 32 sequences per wave (2 streams x 16), 4 waves per block
    const int block = 256;
    const int grid = BB / 128;   // 2048 blocks -> 8192 waves -> 262144 seqs
    lstm_disc_mfma<<<grid, block, 0, stream>>>(values, masks, W_ih, W_hh, b_ih, b_hh,
                                               W1, b1, W2, b2, direct, out);
}